// Round 1
// baseline (6376.275 us; speedup 1.0000x reference)
//
#include <hip/hip_runtime.h>

#define S_LEN 4096
#define LCH   16
#define CED   64
#define CHD   128
#define WED   256
#define WHD   256
#define TAGV  64

typedef _Float16 hf;
typedef _Float16 hf2 __attribute__((ext_vector_type(2)));

__device__ __forceinline__ float dot2f(hf2 a, hf2 b, float acc) {
#if __has_builtin(__builtin_amdgcn_fdot2)
  return __builtin_amdgcn_fdot2(a, b, acc, false);
#else
  return acc + (float)a.x * (float)b.x + (float)a.y * (float)b.y;
#endif
}

__device__ __forceinline__ int dot4i8(int a, int b, int c) {
#if __has_builtin(__builtin_amdgcn_sdot4)
  return __builtin_amdgcn_sdot4(a, b, c, false);
#else
  int r = c;
  r += (int)(signed char)(a)       * (int)(signed char)(b);
  r += (int)(signed char)(a >> 8)  * (int)(signed char)(b >> 8);
  r += (int)(signed char)(a >> 16) * (int)(signed char)(b >> 16);
  r += (int)(signed char)(a >> 24) * (int)(signed char)(b >> 24);
  return r;
#endif
}

__device__ __forceinline__ float sigf(float x) { return 1.f / (1.f + __expf(-x)); }
__device__ __forceinline__ float tanhf_(float x) {
  float a = fabsf(x);
  float e = __expf(-2.f * a);
  float t = (1.f - e) / (1.f + e);
  return copysignf(t, x);
}

// ---------------- Kernel 1: char LSTM (batch 4096, 16 steps, H=128) -------------
// block = 256 threads: u = tid>>1 in [0,128), kh = tid&1 (K-half split).
// 8 words per block. Weights (f16 pairs) resident in VGPRs; h in LDS double-buffer.
__global__ __launch_bounds__(256) void k_char_lstm(
    const int* __restrict__ chars, const int* __restrict__ char_lens,
    const float* __restrict__ char_emb,
    const float* __restrict__ cW_ih, const float* __restrict__ cW_hh,
    const float* __restrict__ cb_ih, const float* __restrict__ cb_hh,
    float* __restrict__ char_final) {
  __shared__ hf emb_s[128 * CED];      // 16 KB, char_emb as f16
  __shared__ hf h_s[2][8][CHD];        // 4 KB
  __shared__ int chars_s[8 * LCH];
  __shared__ int lens_s[8];

  const int tid = threadIdx.x;
  const int u = tid >> 1, kh = tid & 1;
  const int w0 = blockIdx.x * 8;

  for (int i = tid; i < 128 * CED; i += 256) emb_s[i] = (hf)char_emb[i];
  for (int i = tid; i < 8 * LCH; i += 256) chars_s[i] = chars[w0 * LCH + i];
  if (tid < 8) lens_s[tid] = char_lens[w0 + tid];
  {
    hf* hz = &h_s[0][0][0];
    for (int i = tid; i < 8 * CHD; i += 256) hz[i] = (hf)0.f;
  }

  hf2 wih[4][16];
  hf2 whh[4][32];
  float bq[4];
#pragma unroll
  for (int q = 0; q < 4; ++q) {
    const int r = q * CHD + u;
    const float* pi = cW_ih + r * CED + 32 * kh;
#pragma unroll
    for (int j = 0; j < 16; ++j) { hf2 v; v.x = (hf)pi[2*j]; v.y = (hf)pi[2*j+1]; wih[q][j] = v; }
    const float* ph = cW_hh + r * CHD + 64 * kh;
#pragma unroll
    for (int j = 0; j < 32; ++j) { hf2 v; v.x = (hf)ph[2*j]; v.y = (hf)ph[2*j+1]; whh[q][j] = v; }
    bq[q] = cb_ih[r] + cb_hh[r];
  }
  float c[8];
#pragma unroll
  for (int w = 0; w < 8; ++w) c[w] = 0.f;
  __syncthreads();

  for (int t = 0; t < LCH; ++t) {
    const int cur = t & 1, nxt = cur ^ 1;
#pragma unroll
    for (int w = 0; w < 8; ++w) {
      const int cidx = chars_s[w * LCH + t];
      const hf2* xr = (const hf2*)(emb_s + cidx * CED + 32 * kh);
      const hf2* hr = (const hf2*)(&h_s[cur][w][64 * kh]);
      float a0 = 0.f, a1 = 0.f, a2 = 0.f, a3 = 0.f;
#pragma unroll
      for (int j = 0; j < 16; ++j) {
        hf2 xv = xr[j];
        a0 = dot2f(wih[0][j], xv, a0); a1 = dot2f(wih[1][j], xv, a1);
        a2 = dot2f(wih[2][j], xv, a2); a3 = dot2f(wih[3][j], xv, a3);
      }
#pragma unroll
      for (int j = 0; j < 32; ++j) {
        hf2 hv = hr[j];
        a0 = dot2f(whh[0][j], hv, a0); a1 = dot2f(whh[1][j], hv, a1);
        a2 = dot2f(whh[2][j], hv, a2); a3 = dot2f(whh[3][j], hv, a3);
      }
      a0 += __shfl_xor(a0, 1); a1 += __shfl_xor(a1, 1);
      a2 += __shfl_xor(a2, 1); a3 += __shfl_xor(a3, 1);
      const float ig = sigf(a0 + bq[0]);
      const float fg = sigf(a1 + bq[1]);
      const float gg = tanhf_(a2 + bq[2]);
      const float og = sigf(a3 + bq[3]);
      c[w] = fg * c[w] + ig * gg;
      const float hn = og * tanhf_(c[w]);
      if (kh == 0) {
        h_s[nxt][w][u] = (hf)hn;
        if (t == lens_s[w] - 1) char_final[(w0 + w) * CHD + u] = hn;
      }
    }
    __syncthreads();
  }
}

// ---------------- Kernel 2: word-LSTM input part (parallel) ----------------------
// xp[s][tid] = wW_ih[gate(tid)] . [emb(s); char_final(s)] + wb_ih + wb_hh
// gate(tid) = 256*(tid&3) + (tid>>2)  -- permuted so k_word_lstm loads coalesce.
__global__ __launch_bounds__(1024) void k_wxp(
    const int* __restrict__ sent, const float* __restrict__ word_emb,
    const float* __restrict__ char_final,
    const float* __restrict__ wW_ih, const float* __restrict__ wb_ih,
    const float* __restrict__ wb_hh, float* __restrict__ xp) {
  __shared__ float comb[16][WED + CHD];  // 24 KB
  const int tid = threadIdx.x;
  const int s0 = blockIdx.x * 16;
  for (int i = tid; i < 16 * WED; i += 1024) {
    const int w = i / WED, k = i % WED;
    comb[w][k] = word_emb[(long)sent[s0 + w] * WED + k];
  }
  for (int i = tid; i < 16 * CHD; i += 1024) {
    const int w = i / CHD, k = i % CHD;
    comb[w][WED + k] = char_final[(s0 + w) * CHD + k];
  }
  __syncthreads();

  const int gate = 256 * (tid & 3) + (tid >> 2);
  const float bias = wb_ih[gate] + wb_hh[gate];
  float acc[16];
#pragma unroll
  for (int w = 0; w < 16; ++w) acc[w] = bias;
  const float* wrow = wW_ih + gate * (WED + CHD);
  for (int kc = 0; kc < WED + CHD; kc += 64) {
    float wv[64];
#pragma unroll
    for (int i = 0; i < 64; ++i) wv[i] = wrow[kc + i];
#pragma unroll
    for (int w = 0; w < 16; ++w) {
      const float4* cr = (const float4*)&comb[w][kc];
      float a = 0.f;
#pragma unroll
      for (int i = 0; i < 16; ++i) {
        float4 cv = cr[i];
        a += wv[4*i] * cv.x + wv[4*i+1] * cv.y + wv[4*i+2] * cv.z + wv[4*i+3] * cv.w;
      }
      acc[w] += a;
    }
  }
#pragma unroll
  for (int w = 0; w < 16; ++w) xp[(long)(s0 + w) * 1024 + tid] = acc[w];
}

// ---------------- Kernel 3: word LSTM recurrence (serial, 1 block) ---------------
// 1024 threads <-> 1024 gates. q = tid&3 (i,f,g,o), u = tid>>2 (hidden unit).
// W_hh row int8 row-scaled in 64 VGPRs; h int8 in 256 B LDS double-buffer.
__global__ __launch_bounds__(1024) void k_word_lstm(
    const float* __restrict__ wW_hh, const float* __restrict__ xp,
    float* __restrict__ h_all) {
  __shared__ int h_s[2][WHD / 4];  // int8 x4 packed, 256 B per buffer
  const int tid = threadIdx.x;
  const int q = tid & 3, u = tid >> 2;
  const int gate = 256 * q + u;
  const int bl = (tid & 63) & ~3;  // lane base of this unit's 4-lane group

  // quantize my weight row: pass 1 max, pass 2 pack
  const float4* wr4 = (const float4*)(wW_hh + gate * WHD);
  float mx = 0.f;
#pragma unroll
  for (int i = 0; i < 64; ++i) {
    float4 v = wr4[i];
    mx = fmaxf(mx, fmaxf(fmaxf(fabsf(v.x), fabsf(v.y)), fmaxf(fabsf(v.z), fabsf(v.w))));
  }
  const float rs = (mx > 0.f) ? 127.f / mx : 0.f;
  const float dq = (mx > 0.f) ? (mx / 127.f) * (1.f / 127.f) : 0.f;  // w-scale * h-scale
  int wq[64];
#pragma unroll
  for (int i = 0; i < 64; ++i) {
    float4 v = wr4[i];
    const int b0 = (int)rintf(v.x * rs) & 255;
    const int b1 = (int)rintf(v.y * rs) & 255;
    const int b2 = (int)rintf(v.z * rs) & 255;
    const int b3 = (int)rintf(v.w * rs) & 255;
    wq[i] = b0 | (b1 << 8) | (b2 << 16) | (b3 << 24);
  }
  if (tid < WHD / 4) { h_s[0][tid] = 0; h_s[1][tid] = 0; }
  float c = 0.f;
  __syncthreads();

  for (int t = 0; t < S_LEN; ++t) {
    const int cur = t & 1, nxt = cur ^ 1;
    const float xv = xp[(long)t * 1024 + tid];  // issued early, consumed after dot
    int iacc = 0;
    const int4* hp = (const int4*)h_s[cur];
#pragma unroll
    for (int j = 0; j < 16; ++j) {
      int4 hv = hp[j];
      iacc = dot4i8(wq[4*j+0], hv.x, iacc);
      iacc = dot4i8(wq[4*j+1], hv.y, iacc);
      iacc = dot4i8(wq[4*j+2], hv.z, iacc);
      iacc = dot4i8(wq[4*j+3], hv.w, iacc);
    }
    const float gf = (float)iacc * dq + xv;  // xp has both biases folded in
    const float gi = __shfl(gf, bl + 0);
    const float gf2 = __shfl(gf, bl + 1);
    const float gg = __shfl(gf, bl + 2);
    const float go = __shfl(gf, bl + 3);
    const float i_ = sigf(gi), f_ = sigf(gf2), g_ = tanhf_(gg), o_ = sigf(go);
    c = f_ * c + i_ * g_;
    const float hn = o_ * tanhf_(c);
    if (q == 0) {
      h_all[(long)t * WHD + u] = hn;
      ((signed char*)h_s[nxt])[u] = (signed char)(int)rintf(hn * 127.f);
    }
    __syncthreads();
  }
}

// ---------------- Kernel 4: tag projection + log_softmax ------------------------
__global__ __launch_bounds__(64) void k_tag(
    const float* __restrict__ h_all, const float* __restrict__ tagW,
    const float* __restrict__ tagb, float* __restrict__ out) {
  __shared__ float hrow[WHD];
  const int s = blockIdx.x, t = threadIdx.x;
  for (int i = t; i < WHD; i += 64) hrow[i] = h_all[(long)s * WHD + i];
  __syncthreads();
  const float4* wr = (const float4*)(tagW + t * WHD);
  const float4* hr = (const float4*)hrow;
  float a = tagb[t];
#pragma unroll
  for (int i = 0; i < 64; ++i) {
    float4 w4 = wr[i], h4 = hr[i];
    a += w4.x * h4.x + w4.y * h4.y + w4.z * h4.z + w4.w * h4.w;
  }
  float m = a;
#pragma unroll
  for (int d = 1; d < 64; d <<= 1) m = fmaxf(m, __shfl_xor(m, d));
  const float e = __expf(a - m);
  float sum = e;
#pragma unroll
  for (int d = 1; d < 64; d <<= 1) sum += __shfl_xor(sum, d);
  out[(long)s * TAGV + t] = (a - m) - logf(sum);
}

extern "C" void kernel_launch(void* const* d_in, const int* in_sizes, int n_in,
                              void* d_out, int out_size, void* d_ws, size_t ws_size,
                              hipStream_t stream) {
  const int* sent       = (const int*)d_in[0];
  const int* chars      = (const int*)d_in[1];
  const int* char_lens  = (const int*)d_in[2];
  const float* char_emb = (const float*)d_in[3];
  const float* word_emb = (const float*)d_in[4];
  const float* cW_ih    = (const float*)d_in[5];
  const float* cW_hh    = (const float*)d_in[6];
  const float* cb_ih    = (const float*)d_in[7];
  const float* cb_hh    = (const float*)d_in[8];
  const float* wW_ih    = (const float*)d_in[9];
  const float* wW_hh    = (const float*)d_in[10];
  const float* wb_ih    = (const float*)d_in[11];
  const float* wb_hh    = (const float*)d_in[12];
  const float* tagW     = (const float*)d_in[13];
  const float* tagb     = (const float*)d_in[14];
  float* out = (float*)d_out;

  char* ws = (char*)d_ws;
  float* char_final = (float*)ws;                          // 4096*128*4  = 2 MB
  float* xp         = (float*)(ws + ((size_t)2 << 20));    // 4096*1024*4 = 16 MB
  float* h_all      = (float*)(ws + ((size_t)20 << 20));   // 4096*256*4  = 4 MB

  hipLaunchKernelGGL(k_char_lstm, dim3(512), dim3(256), 0, stream,
                     chars, char_lens, char_emb, cW_ih, cW_hh, cb_ih, cb_hh, char_final);
  hipLaunchKernelGGL(k_wxp, dim3(256), dim3(1024), 0, stream,
                     sent, word_emb, char_final, wW_ih, wb_ih, wb_hh, xp);
  hipLaunchKernelGGL(k_word_lstm, dim3(1), dim3(1024), 0, stream, wW_hh, xp, h_all);
  hipLaunchKernelGGL(k_tag, dim3(4096), dim3(64), 0, stream, h_all, tagW, tagb, out);
}

// Round 2
// 4323.070 us; speedup vs baseline: 1.4749x; 1.4749x over previous
//
#include <hip/hip_runtime.h>

#define S_LEN 4096
#define LCH   16
#define CED   64
#define CHD   128
#define WED   256
#define WHD   256
#define TAGV  64

typedef _Float16 hf;
typedef _Float16 hf2 __attribute__((ext_vector_type(2)));

__device__ __forceinline__ float dot2f(hf2 a, hf2 b, float acc) {
#if __has_builtin(__builtin_amdgcn_fdot2)
  return __builtin_amdgcn_fdot2(a, b, acc, false);
#else
  return acc + (float)a.x * (float)b.x + (float)a.y * (float)b.y;
#endif
}

__device__ __forceinline__ int dot4i8(int a, int b, int c) {
#if __has_builtin(__builtin_amdgcn_sdot4)
  return __builtin_amdgcn_sdot4(a, b, c, false);
#else
  int r = c;
  r += (int)(signed char)(a)       * (int)(signed char)(b);
  r += (int)(signed char)(a >> 8)  * (int)(signed char)(b >> 8);
  r += (int)(signed char)(a >> 16) * (int)(signed char)(b >> 16);
  r += (int)(signed char)(a >> 24) * (int)(signed char)(b >> 24);
  return r;
#endif
}

__device__ __forceinline__ float ex2(float x) {
#if __has_builtin(__builtin_amdgcn_exp2f)
  return __builtin_amdgcn_exp2f(x);
#else
  return __exp2f(x);
#endif
}
__device__ __forceinline__ float rcp_(float x) {
#if __has_builtin(__builtin_amdgcn_rcpf)
  return __builtin_amdgcn_rcpf(x);
#else
  return 1.f / x;
#endif
}

template <int C> __device__ __forceinline__ int dppi(int x) {
  return __builtin_amdgcn_mov_dpp(x, C, 0xf, 0xf, false);
}
template <int C> __device__ __forceinline__ float dppf(float x) {
  return __int_as_float(__builtin_amdgcn_mov_dpp(__float_as_int(x), C, 0xf, 0xf, false));
}
// quad_perm ctrl bytes: xor1=[1,0,3,2]=0xB1, xor2=[2,3,0,1]=0x4E,
// bcast lane0..3 = 0x00,0x55,0xAA,0xFF

__device__ __forceinline__ float sigf(float x) { return 1.f / (1.f + __expf(-x)); }
__device__ __forceinline__ float tanhf_(float x) {
  float a = fabsf(x);
  float e = __expf(-2.f * a);
  float t = (1.f - e) / (1.f + e);
  return copysignf(t, x);
}

// ---------------- Kernel 1: char LSTM (batch 4096, 16 steps, H=128) -------------
__global__ __launch_bounds__(256) void k_char_lstm(
    const int* __restrict__ chars, const int* __restrict__ char_lens,
    const float* __restrict__ char_emb,
    const float* __restrict__ cW_ih, const float* __restrict__ cW_hh,
    const float* __restrict__ cb_ih, const float* __restrict__ cb_hh,
    float* __restrict__ char_final) {
  __shared__ hf emb_s[128 * CED];
  __shared__ hf h_s[2][8][CHD];
  __shared__ int chars_s[8 * LCH];
  __shared__ int lens_s[8];

  const int tid = threadIdx.x;
  const int u = tid >> 1, kh = tid & 1;
  const int w0 = blockIdx.x * 8;

  for (int i = tid; i < 128 * CED; i += 256) emb_s[i] = (hf)char_emb[i];
  for (int i = tid; i < 8 * LCH; i += 256) chars_s[i] = chars[w0 * LCH + i];
  if (tid < 8) lens_s[tid] = char_lens[w0 + tid];
  {
    hf* hz = &h_s[0][0][0];
    for (int i = tid; i < 8 * CHD; i += 256) hz[i] = (hf)0.f;
  }

  hf2 wih[4][16];
  hf2 whh[4][32];
  float bq[4];
#pragma unroll
  for (int q = 0; q < 4; ++q) {
    const int r = q * CHD + u;
    const float* pi = cW_ih + r * CED + 32 * kh;
#pragma unroll
    for (int j = 0; j < 16; ++j) { hf2 v; v.x = (hf)pi[2*j]; v.y = (hf)pi[2*j+1]; wih[q][j] = v; }
    const float* ph = cW_hh + r * CHD + 64 * kh;
#pragma unroll
    for (int j = 0; j < 32; ++j) { hf2 v; v.x = (hf)ph[2*j]; v.y = (hf)ph[2*j+1]; whh[q][j] = v; }
    bq[q] = cb_ih[r] + cb_hh[r];
  }
  float c[8];
#pragma unroll
  for (int w = 0; w < 8; ++w) c[w] = 0.f;
  __syncthreads();

  for (int t = 0; t < LCH; ++t) {
    const int cur = t & 1, nxt = cur ^ 1;
#pragma unroll
    for (int w = 0; w < 8; ++w) {
      const int cidx = chars_s[w * LCH + t];
      const hf2* xr = (const hf2*)(emb_s + cidx * CED + 32 * kh);
      const hf2* hr = (const hf2*)(&h_s[cur][w][64 * kh]);
      float a0 = 0.f, a1 = 0.f, a2 = 0.f, a3 = 0.f;
#pragma unroll
      for (int j = 0; j < 16; ++j) {
        hf2 xv = xr[j];
        a0 = dot2f(wih[0][j], xv, a0); a1 = dot2f(wih[1][j], xv, a1);
        a2 = dot2f(wih[2][j], xv, a2); a3 = dot2f(wih[3][j], xv, a3);
      }
#pragma unroll
      for (int j = 0; j < 32; ++j) {
        hf2 hv = hr[j];
        a0 = dot2f(whh[0][j], hv, a0); a1 = dot2f(whh[1][j], hv, a1);
        a2 = dot2f(whh[2][j], hv, a2); a3 = dot2f(whh[3][j], hv, a3);
      }
      a0 += __shfl_xor(a0, 1); a1 += __shfl_xor(a1, 1);
      a2 += __shfl_xor(a2, 1); a3 += __shfl_xor(a3, 1);
      const float ig = sigf(a0 + bq[0]);
      const float fg = sigf(a1 + bq[1]);
      const float gg = tanhf_(a2 + bq[2]);
      const float og = sigf(a3 + bq[3]);
      c[w] = fg * c[w] + ig * gg;
      const float hn = og * tanhf_(c[w]);
      if (kh == 0) {
        h_s[nxt][w][u] = (hf)hn;
        if (t == lens_s[w] - 1) char_final[(w0 + w) * CHD + u] = hn;
      }
    }
    __syncthreads();
  }
}

// ---------------- Kernel 2: word-LSTM input part (parallel) ----------------------
__global__ __launch_bounds__(1024) void k_wxp(
    const int* __restrict__ sent, const float* __restrict__ word_emb,
    const float* __restrict__ char_final,
    const float* __restrict__ wW_ih, const float* __restrict__ wb_ih,
    const float* __restrict__ wb_hh, float* __restrict__ xp) {
  __shared__ float comb[16][WED + CHD];
  const int tid = threadIdx.x;
  const int s0 = blockIdx.x * 16;
  for (int i = tid; i < 16 * WED; i += 1024) {
    const int w = i / WED, k = i % WED;
    comb[w][k] = word_emb[(long)sent[s0 + w] * WED + k];
  }
  for (int i = tid; i < 16 * CHD; i += 1024) {
    const int w = i / CHD, k = i % CHD;
    comb[w][WED + k] = char_final[(s0 + w) * CHD + k];
  }
  __syncthreads();

  const int gate = 256 * (tid & 3) + (tid >> 2);
  const float bias = wb_ih[gate] + wb_hh[gate];
  float acc[16];
#pragma unroll
  for (int w = 0; w < 16; ++w) acc[w] = bias;
  const float* wrow = wW_ih + gate * (WED + CHD);
  for (int kc = 0; kc < WED + CHD; kc += 64) {
    float wv[64];
#pragma unroll
    for (int i = 0; i < 64; ++i) wv[i] = wrow[kc + i];
#pragma unroll
    for (int w = 0; w < 16; ++w) {
      const float4* cr = (const float4*)&comb[w][kc];
      float a = 0.f;
#pragma unroll
      for (int i = 0; i < 16; ++i) {
        float4 cv = cr[i];
        a += wv[4*i] * cv.x + wv[4*i+1] * cv.y + wv[4*i+2] * cv.z + wv[4*i+3] * cv.w;
      }
      acc[w] += a;
    }
  }
#pragma unroll
  for (int w = 0; w < 16; ++w) xp[(long)(s0 + w) * 1024 + tid] = acc[w];
}

// ---------------- Kernel 3: word LSTM recurrence (serial, 1 block) ---------------
// 1024 threads; unit u = tid>>2, lane-in-quad l = tid&3.
// Lane l dots ALL 4 gates of unit u over k-slice [64l, 64l+64) (int8, sdot4),
// quad all-reduce via DPP, one activation per lane (gate l), DPP gather,
// raw s_barrier (lgkmcnt only — no vmcnt drain), xp prefetched 4 steps ahead.
__global__ __launch_bounds__(1024, 4) void k_word_lstm(
    const float* __restrict__ wW_hh, const float* __restrict__ xp,
    float* __restrict__ h_all) {
  __shared__ int4 hq[2][16];  // two 256-B int8 h buffers
  const int tid = threadIdx.x;
  const int u = tid >> 2;
  const int l = tid & 3;

  // ---- pass 1: per-gate row max (slice max, then quad all-reduce max) ----
  float mx0 = 0.f, mx1 = 0.f, mx2 = 0.f, mx3 = 0.f;
#pragma unroll
  for (int q = 0; q < 4; ++q) {
    const float4* wr = (const float4*)(wW_hh + (long)(q * WHD + u) * WHD + l * 64);
    float m = 0.f;
#pragma unroll
    for (int j = 0; j < 16; ++j) {
      float4 v = wr[j];
      m = fmaxf(m, fmaxf(fmaxf(fabsf(v.x), fabsf(v.y)), fmaxf(fabsf(v.z), fabsf(v.w))));
    }
    if (q == 0) mx0 = m; else if (q == 1) mx1 = m; else if (q == 2) mx2 = m; else mx3 = m;
  }
  mx0 = fmaxf(mx0, dppf<0xB1>(mx0)); mx0 = fmaxf(mx0, dppf<0x4E>(mx0));
  mx1 = fmaxf(mx1, dppf<0xB1>(mx1)); mx1 = fmaxf(mx1, dppf<0x4E>(mx1));
  mx2 = fmaxf(mx2, dppf<0xB1>(mx2)); mx2 = fmaxf(mx2, dppf<0x4E>(mx2));
  mx3 = fmaxf(mx3, dppf<0xB1>(mx3)); mx3 = fmaxf(mx3, dppf<0x4E>(mx3));

  // ---- pass 2: quantize my 4 gate-slices with the row scales ----
  int wq[4][16];
  {
    float rs[4];
    rs[0] = (mx0 > 0.f) ? 127.f / mx0 : 0.f;
    rs[1] = (mx1 > 0.f) ? 127.f / mx1 : 0.f;
    rs[2] = (mx2 > 0.f) ? 127.f / mx2 : 0.f;
    rs[3] = (mx3 > 0.f) ? 127.f / mx3 : 0.f;
#pragma unroll
    for (int q = 0; q < 4; ++q) {
      const float4* wr = (const float4*)(wW_hh + (long)(q * WHD + u) * WHD + l * 64);
      const float r = rs[q];
#pragma unroll
      for (int j = 0; j < 16; ++j) {
        float4 v = wr[j];
        const int b0 = (int)rintf(v.x * r) & 255;
        const int b1 = (int)rintf(v.y * r) & 255;
        const int b2 = (int)rintf(v.z * r) & 255;
        const int b3 = (int)rintf(v.w * r) & 255;
        wq[q][j] = b0 | (b1 << 8) | (b2 << 16) | (b3 << 24);
      }
    }
  }
  // own-gate dequant scale (w-scale * h-scale) and activation constants
  const float mxa = (l & 1) ? mx1 : mx0;
  const float mxb = (l & 1) ? mx3 : mx2;
  const float mx_own = (l & 2) ? mxb : mxa;
  const float dq_own = mx_own * (1.f / (127.f * 127.f));
  // act = s*sigmoid(m*x)+d ; tanh(x)=2*sigmoid(2x)-1 (gate 2 is tanh)
  const float em = (l == 2) ? -2.885390082f : -1.442695041f;  // -m*log2(e)
  const float s_ = (l == 2) ? 2.f : 1.f;
  const float d_ = (l == 2) ? -1.f : 0.f;

  if (tid < 32) { int4 z; z.x = z.y = z.z = z.w = 0; ((int4*)hq)[tid] = z; }
  float c = 0.f;
  __syncthreads();

  const float* xpp = xp + tid;
  float* hout = h_all + u;

#define STEP(T, XV, CUR) do {                                                  \
    const int4* hp_ = &hq[CUR][4 * l];                                         \
    int4 hv0 = hp_[0], hv1 = hp_[1], hv2 = hp_[2], hv3 = hp_[3];               \
    int hh[16] = {hv0.x, hv0.y, hv0.z, hv0.w, hv1.x, hv1.y, hv1.z, hv1.w,      \
                  hv2.x, hv2.y, hv2.z, hv2.w, hv3.x, hv3.y, hv3.z, hv3.w};     \
    int a0 = 0, a1 = 0, a2 = 0, a3 = 0;                                        \
    _Pragma("unroll")                                                          \
    for (int j = 0; j < 16; ++j) {                                             \
      a0 = dot4i8(wq[0][j], hh[j], a0);                                        \
      a1 = dot4i8(wq[1][j], hh[j], a1);                                        \
      a2 = dot4i8(wq[2][j], hh[j], a2);                                        \
      a3 = dot4i8(wq[3][j], hh[j], a3);                                        \
    }                                                                          \
    a0 += dppi<0xB1>(a0); a1 += dppi<0xB1>(a1);                                \
    a2 += dppi<0xB1>(a2); a3 += dppi<0xB1>(a3);                                \
    a0 += dppi<0x4E>(a0); a1 += dppi<0x4E>(a1);                                \
    a2 += dppi<0x4E>(a2); a3 += dppi<0x4E>(a3);                                \
    const int sa = (l & 1) ? a1 : a0;                                          \
    const int sb = (l & 1) ? a3 : a2;                                          \
    const int aown = (l & 2) ? sb : sa;                                        \
    const float gf = fmaf((float)aown, dq_own, (XV));                          \
    const float sg = rcp_(1.f + ex2(em * gf));                                 \
    const float act = fmaf(s_, sg, d_);                                        \
    const float i_ = dppf<0x00>(act);                                          \
    const float f_ = dppf<0x55>(act);                                          \
    const float g_ = dppf<0xAA>(act);                                          \
    const float o_ = dppf<0xFF>(act);                                          \
    c = fmaf(f_, c, i_ * g_);                                                  \
    const float tc = fmaf(2.f, rcp_(1.f + ex2(-2.885390082f * c)), -1.f);      \
    const float hn = o_ * tc;                                                  \
    if (l == 0) ((signed char*)&hq[(CUR) ^ 1][0])[u] =                         \
        (signed char)(int)rintf(hn * 127.f);                                   \
    if (l == 1) hout[(long)(T) * WHD] = hn;                                    \
    asm volatile("s_waitcnt lgkmcnt(0)\n\ts_barrier" ::: "memory");            \
  } while (0)

  float xA0 = xpp[0], xA1 = xpp[1024], xA2 = xpp[2048], xA3 = xpp[3072];
  for (int t0 = 0; t0 < S_LEN; t0 += 8) {
    const float* pb = xpp + (long)(t0 + 4) * 1024;
    const float xB0 = pb[0], xB1 = pb[1024], xB2 = pb[2048], xB3 = pb[3072];
    STEP(t0 + 0, xA0, 0); STEP(t0 + 1, xA1, 1);
    STEP(t0 + 2, xA2, 0); STEP(t0 + 3, xA3, 1);
    if (t0 + 8 < S_LEN) {
      const float* pa = xpp + (long)(t0 + 8) * 1024;
      xA0 = pa[0]; xA1 = pa[1024]; xA2 = pa[2048]; xA3 = pa[3072];
    }
    STEP(t0 + 4, xB0, 0); STEP(t0 + 5, xB1, 1);
    STEP(t0 + 6, xB2, 0); STEP(t0 + 7, xB3, 1);
  }
#undef STEP
}

// ---------------- Kernel 4: tag projection + log_softmax ------------------------
__global__ __launch_bounds__(64) void k_tag(
    const float* __restrict__ h_all, const float* __restrict__ tagW,
    const float* __restrict__ tagb, float* __restrict__ out) {
  __shared__ float hrow[WHD];
  const int s = blockIdx.x, t = threadIdx.x;
  for (int i = t; i < WHD; i += 64) hrow[i] = h_all[(long)s * WHD + i];
  __syncthreads();
  const float4* wr = (const float4*)(tagW + t * WHD);
  const float4* hr = (const float4*)hrow;
  float a = tagb[t];
#pragma unroll
  for (int i = 0; i < 64; ++i) {
    float4 w4 = wr[i], h4 = hr[i];
    a += w4.x * h4.x + w4.y * h4.y + w4.z * h4.z + w4.w * h4.w;
  }
  float m = a;
#pragma unroll
  for (int d = 1; d < 64; d <<= 1) m = fmaxf(m, __shfl_xor(m, d));
  const float e = __expf(a - m);
  float sum = e;
#pragma unroll
  for (int d = 1; d < 64; d <<= 1) sum += __shfl_xor(sum, d);
  out[(long)s * TAGV + t] = (a - m) - logf(sum);
}

extern "C" void kernel_launch(void* const* d_in, const int* in_sizes, int n_in,
                              void* d_out, int out_size, void* d_ws, size_t ws_size,
                              hipStream_t stream) {
  const int* sent       = (const int*)d_in[0];
  const int* chars      = (const int*)d_in[1];
  const int* char_lens  = (const int*)d_in[2];
  const float* char_emb = (const float*)d_in[3];
  const float* word_emb = (const float*)d_in[4];
  const float* cW_ih    = (const float*)d_in[5];
  const float* cW_hh    = (const float*)d_in[6];
  const float* cb_ih    = (const float*)d_in[7];
  const float* cb_hh    = (const float*)d_in[8];
  const float* wW_ih    = (const float*)d_in[9];
  const float* wW_hh    = (const float*)d_in[10];
  const float* wb_ih    = (const float*)d_in[11];
  const float* wb_hh    = (const float*)d_in[12];
  const float* tagW     = (const float*)d_in[13];
  const float* tagb     = (const float*)d_in[14];
  float* out = (float*)d_out;

  char* ws = (char*)d_ws;
  float* char_final = (float*)ws;                          // 4096*128*4  = 2 MB
  float* xp         = (float*)(ws + ((size_t)2 << 20));    // 4096*1024*4 = 16 MB
  float* h_all      = (float*)(ws + ((size_t)20 << 20));   // 4096*256*4  = 4 MB

  hipLaunchKernelGGL(k_char_lstm, dim3(512), dim3(256), 0, stream,
                     chars, char_lens, char_emb, cW_ih, cW_hh, cb_ih, cb_hh, char_final);
  hipLaunchKernelGGL(k_wxp, dim3(256), dim3(1024), 0, stream,
                     sent, word_emb, char_final, wW_ih, wb_ih, wb_hh, xp);
  hipLaunchKernelGGL(k_word_lstm, dim3(1), dim3(1024), 0, stream, wW_hh, xp, h_all);
  hipLaunchKernelGGL(k_tag, dim3(4096), dim3(64), 0, stream, h_all, tagW, tagb, out);
}

// Round 3
// 4128.893 us; speedup vs baseline: 1.5443x; 1.0470x over previous
//
#include <hip/hip_runtime.h>

#define S_LEN 4096
#define LCH   16
#define CED   64
#define CHD   128
#define WED   256
#define WHD   256
#define TAGV  64

typedef _Float16 hf;
typedef _Float16 hf2 __attribute__((ext_vector_type(2)));

__device__ __forceinline__ float dot2f(hf2 a, hf2 b, float acc) {
#if __has_builtin(__builtin_amdgcn_fdot2)
  return __builtin_amdgcn_fdot2(a, b, acc, false);
#else
  return acc + (float)a.x * (float)b.x + (float)a.y * (float)b.y;
#endif
}

__device__ __forceinline__ int dot4i8(int a, int b, int c) {
#if __has_builtin(__builtin_amdgcn_sdot4)
  return __builtin_amdgcn_sdot4(a, b, c, false);
#else
  int r = c;
  r += (int)(signed char)(a)       * (int)(signed char)(b);
  r += (int)(signed char)(a >> 8)  * (int)(signed char)(b >> 8);
  r += (int)(signed char)(a >> 16) * (int)(signed char)(b >> 16);
  r += (int)(signed char)(a >> 24) * (int)(signed char)(b >> 24);
  return r;
#endif
}

__device__ __forceinline__ float ex2(float x) {
#if __has_builtin(__builtin_amdgcn_exp2f)
  return __builtin_amdgcn_exp2f(x);
#else
  return __exp2f(x);
#endif
}
__device__ __forceinline__ float rcp_(float x) {
#if __has_builtin(__builtin_amdgcn_rcpf)
  return __builtin_amdgcn_rcpf(x);
#else
  return 1.f / x;
#endif
}

template <int C> __device__ __forceinline__ int dppi(int x) {
  return __builtin_amdgcn_mov_dpp(x, C, 0xf, 0xf, false);
}
template <int C> __device__ __forceinline__ float dppf(float x) {
  return __int_as_float(__builtin_amdgcn_mov_dpp(__float_as_int(x), C, 0xf, 0xf, false));
}
// quad_perm ctrl: xor1=0xB1, xor2=0x4E, bcast lane0..3 = 0x00,0x55,0xAA,0xFF

__device__ __forceinline__ float sigf(float x) { return 1.f / (1.f + __expf(-x)); }
__device__ __forceinline__ float tanhf_(float x) {
  float a = fabsf(x);
  float e = __expf(-2.f * a);
  float t = (1.f - e) / (1.f + e);
  return copysignf(t, x);
}

// ---------------- Kernel 1: char LSTM (batch 4096, 16 steps, H=128) -------------
__global__ __launch_bounds__(256) void k_char_lstm(
    const int* __restrict__ chars, const int* __restrict__ char_lens,
    const float* __restrict__ char_emb,
    const float* __restrict__ cW_ih, const float* __restrict__ cW_hh,
    const float* __restrict__ cb_ih, const float* __restrict__ cb_hh,
    float* __restrict__ char_final) {
  __shared__ hf emb_s[128 * CED];
  __shared__ hf h_s[2][8][CHD];
  __shared__ int chars_s[8 * LCH];
  __shared__ int lens_s[8];

  const int tid = threadIdx.x;
  const int u = tid >> 1, kh = tid & 1;
  const int w0 = blockIdx.x * 8;

  for (int i = tid; i < 128 * CED; i += 256) emb_s[i] = (hf)char_emb[i];
  for (int i = tid; i < 8 * LCH; i += 256) chars_s[i] = chars[w0 * LCH + i];
  if (tid < 8) lens_s[tid] = char_lens[w0 + tid];
  {
    hf* hz = &h_s[0][0][0];
    for (int i = tid; i < 8 * CHD; i += 256) hz[i] = (hf)0.f;
  }

  hf2 wih[4][16];
  hf2 whh[4][32];
  float bq[4];
#pragma unroll
  for (int q = 0; q < 4; ++q) {
    const int r = q * CHD + u;
    const float* pi = cW_ih + r * CED + 32 * kh;
#pragma unroll
    for (int j = 0; j < 16; ++j) { hf2 v; v.x = (hf)pi[2*j]; v.y = (hf)pi[2*j+1]; wih[q][j] = v; }
    const float* ph = cW_hh + r * CHD + 64 * kh;
#pragma unroll
    for (int j = 0; j < 32; ++j) { hf2 v; v.x = (hf)ph[2*j]; v.y = (hf)ph[2*j+1]; whh[q][j] = v; }
    bq[q] = cb_ih[r] + cb_hh[r];
  }
  float c[8];
#pragma unroll
  for (int w = 0; w < 8; ++w) c[w] = 0.f;
  __syncthreads();

  for (int t = 0; t < LCH; ++t) {
    const int cur = t & 1, nxt = cur ^ 1;
#pragma unroll
    for (int w = 0; w < 8; ++w) {
      const int cidx = chars_s[w * LCH + t];
      const hf2* xr = (const hf2*)(emb_s + cidx * CED + 32 * kh);
      const hf2* hr = (const hf2*)(&h_s[cur][w][64 * kh]);
      float a0 = 0.f, a1 = 0.f, a2 = 0.f, a3 = 0.f;
#pragma unroll
      for (int j = 0; j < 16; ++j) {
        hf2 xv = xr[j];
        a0 = dot2f(wih[0][j], xv, a0); a1 = dot2f(wih[1][j], xv, a1);
        a2 = dot2f(wih[2][j], xv, a2); a3 = dot2f(wih[3][j], xv, a3);
      }
#pragma unroll
      for (int j = 0; j < 32; ++j) {
        hf2 hv = hr[j];
        a0 = dot2f(whh[0][j], hv, a0); a1 = dot2f(whh[1][j], hv, a1);
        a2 = dot2f(whh[2][j], hv, a2); a3 = dot2f(whh[3][j], hv, a3);
      }
      a0 += __shfl_xor(a0, 1); a1 += __shfl_xor(a1, 1);
      a2 += __shfl_xor(a2, 1); a3 += __shfl_xor(a3, 1);
      const float ig = sigf(a0 + bq[0]);
      const float fg = sigf(a1 + bq[1]);
      const float gg = tanhf_(a2 + bq[2]);
      const float og = sigf(a3 + bq[3]);
      c[w] = fg * c[w] + ig * gg;
      const float hn = og * tanhf_(c[w]);
      if (kh == 0) {
        h_s[nxt][w][u] = (hf)hn;
        if (t == lens_s[w] - 1) char_final[(w0 + w) * CHD + u] = hn;
      }
    }
    __syncthreads();
  }
}

// ---------------- Kernel 2: word-LSTM input part (parallel) ----------------------
// slot(tid): e = tid>>9, r = tid&511, p = r>>2, q = r&3 -> gate = 256q + 2p + e.
// k_word_lstm thread t reads slots t (unit 2p) and 512+t (unit 2p+1).
__global__ __launch_bounds__(1024) void k_wxp(
    const int* __restrict__ sent, const float* __restrict__ word_emb,
    const float* __restrict__ char_final,
    const float* __restrict__ wW_ih, const float* __restrict__ wb_ih,
    const float* __restrict__ wb_hh, float* __restrict__ xp) {
  __shared__ float comb[16][WED + CHD];
  const int tid = threadIdx.x;
  const int s0 = blockIdx.x * 16;
  for (int i = tid; i < 16 * WED; i += 1024) {
    const int w = i / WED, k = i % WED;
    comb[w][k] = word_emb[(long)sent[s0 + w] * WED + k];
  }
  for (int i = tid; i < 16 * CHD; i += 1024) {
    const int w = i / CHD, k = i % CHD;
    comb[w][WED + k] = char_final[(s0 + w) * CHD + k];
  }
  __syncthreads();

  const int e = tid >> 9, r = tid & 511;
  const int gate = 256 * (r & 3) + 2 * (r >> 2) + e;
  const float bias = wb_ih[gate] + wb_hh[gate];
  float acc[16];
#pragma unroll
  for (int w = 0; w < 16; ++w) acc[w] = bias;
  const float* wrow = wW_ih + gate * (WED + CHD);
  for (int kc = 0; kc < WED + CHD; kc += 64) {
    float wv[64];
#pragma unroll
    for (int i = 0; i < 64; ++i) wv[i] = wrow[kc + i];
#pragma unroll
    for (int w = 0; w < 16; ++w) {
      const float4* cr = (const float4*)&comb[w][kc];
      float a = 0.f;
#pragma unroll
      for (int i = 0; i < 16; ++i) {
        float4 cv = cr[i];
        a += wv[4*i] * cv.x + wv[4*i+1] * cv.y + wv[4*i+2] * cv.z + wv[4*i+3] * cv.w;
      }
      acc[w] += a;
    }
  }
#pragma unroll
  for (int w = 0; w < 16; ++w) xp[(long)(s0 + w) * 1024 + tid] = acc[w];
}

// ---------------- Kernel 3: word LSTM recurrence (serial, 1 block) ---------------
// 512 threads (8 waves, 2/SIMD -> 256-VGPR budget). Quad p owns units 2p, 2p+1.
// Lane l dots all 8 gate-rows over k-slice [64l,64l+64) (int8 sdot4, weights in
// VGPRs), transpose-reduce (xor1/xor2 butterfly) lands gate l's full dot in lane
// l. One activation pair per lane, quad-bcast gather, c kept redundantly in all
// 4 lanes. h int8 in 512-B LDS flip-flop; raw lgkmcnt-only barrier per step.
__global__ __launch_bounds__(512, 2) void k_word_lstm(
    const float* __restrict__ wW_hh, const float* __restrict__ xp,
    float* __restrict__ h_all) {
  __shared__ int hq[2][WHD / 4];  // int8-packed h, 256 B per buffer
  const int t = threadIdx.x;
  const int p = t >> 2, l = t & 3;
  const int uA = 2 * p, uB = 2 * p + 1;

  // ---- preamble: per-row max + int8 quantize, 8 rows x 16 words each ----
  int wqA0[16], wqA1[16], wqA2[16], wqA3[16];
  int wqB0[16], wqB1[16], wqB2[16], wqB3[16];
  float mA0, mA1, mA2, mA3, mB0, mB1, mB2, mB3;

#define ROWMAX(mdst, row) do {                                                  \
    const float4* wr_ = (const float4*)(wW_hh + (long)(row) * WHD + 64 * l);    \
    float m_ = 0.f;                                                             \
    _Pragma("unroll")                                                           \
    for (int j = 0; j < 16; ++j) {                                              \
      float4 v = wr_[j];                                                        \
      m_ = fmaxf(m_, fmaxf(fmaxf(fabsf(v.x), fabsf(v.y)),                       \
                           fmaxf(fabsf(v.z), fabsf(v.w))));                     \
    }                                                                           \
    m_ = fmaxf(m_, dppf<0xB1>(m_)); m_ = fmaxf(m_, dppf<0x4E>(m_));             \
    (mdst) = m_;                                                                \
  } while (0)

  ROWMAX(mA0, 0 * WHD + uA); ROWMAX(mA1, 1 * WHD + uA);
  ROWMAX(mA2, 2 * WHD + uA); ROWMAX(mA3, 3 * WHD + uA);
  ROWMAX(mB0, 0 * WHD + uB); ROWMAX(mB1, 1 * WHD + uB);
  ROWMAX(mB2, 2 * WHD + uB); ROWMAX(mB3, 3 * WHD + uB);
#undef ROWMAX

#define QROW(dst, row, mreg) do {                                               \
    const float4* wr_ = (const float4*)(wW_hh + (long)(row) * WHD + 64 * l);    \
    const float r_ = ((mreg) > 0.f) ? 127.f / (mreg) : 0.f;                     \
    _Pragma("unroll")                                                           \
    for (int j = 0; j < 16; ++j) {                                              \
      float4 v = wr_[j];                                                        \
      const int b0 = (int)rintf(v.x * r_) & 255;                                \
      const int b1 = (int)rintf(v.y * r_) & 255;                                \
      const int b2 = (int)rintf(v.z * r_) & 255;                                \
      const int b3 = (int)rintf(v.w * r_) & 255;                                \
      dst[j] = b0 | (b1 << 8) | (b2 << 16) | (b3 << 24);                        \
    }                                                                           \
  } while (0)

  QROW(wqA0, 0 * WHD + uA, mA0); QROW(wqA1, 1 * WHD + uA, mA1);
  QROW(wqA2, 2 * WHD + uA, mA2); QROW(wqA3, 3 * WHD + uA, mA3);
  QROW(wqB0, 0 * WHD + uB, mB0); QROW(wqB1, 1 * WHD + uB, mB1);
  QROW(wqB2, 2 * WHD + uB, mB2); QROW(wqB3, 3 * WHD + uB, mB3);
#undef QROW

  // own-gate (gate-type == l) dequant scale: w_scale * h_scale
  const float mselA = (l & 1) ? ((l & 2) ? mA3 : mA1) : ((l & 2) ? mA2 : mA0);
  const float mselB = (l & 1) ? ((l & 2) ? mB3 : mB1) : ((l & 2) ? mB2 : mB0);
  const float dqA = mselA * (1.f / (127.f * 127.f));
  const float dqB = mselB * (1.f / (127.f * 127.f));
  // act = s*sigmoid(m*x)+d ; gate-type 2 (g) is tanh
  const float em = (l == 2) ? -2.885390082f : -1.442695041f;
  const float s_ = (l == 2) ? 2.f : 1.f;
  const float d_ = (l == 2) ? -1.f : 0.f;

  if (t < 32) { int4 z; z.x = z.y = z.z = z.w = 0; ((int4*)hq)[t] = z; }
  float cA = 0.f, cB = 0.f;
  __syncthreads();

  const float* xbase = xp + t;  // slot t = gate l of unit 2p; +512 = unit 2p+1
  float* hout = h_all + 2 * p;

#define DOT4W(j, W) do {                                                        \
    aA0 = dot4i8(wqA0[j], (W), aA0); aA1 = dot4i8(wqA1[j], (W), aA1);           \
    aA2 = dot4i8(wqA2[j], (W), aA2); aA3 = dot4i8(wqA3[j], (W), aA3);           \
    aB0 = dot4i8(wqB0[j], (W), aB0); aB1 = dot4i8(wqB1[j], (W), aB1);           \
    aB2 = dot4i8(wqB2[j], (W), aB2); aB3 = dot4i8(wqB3[j], (W), aB3);           \
  } while (0)

#define STEP(T, XA, XB, CUR) do {                                               \
    const int4* hp_ = (const int4*)(&hq[CUR][0]) + l * 4;                       \
    int4 h0 = hp_[0], h1 = hp_[1], h2 = hp_[2], h3 = hp_[3];                    \
    int aA0 = 0, aA1 = 0, aA2 = 0, aA3 = 0;                                     \
    int aB0 = 0, aB1 = 0, aB2 = 0, aB3 = 0;                                     \
    DOT4W(0, h0.x);  DOT4W(1, h0.y);  DOT4W(2, h0.z);  DOT4W(3, h0.w);          \
    DOT4W(4, h1.x);  DOT4W(5, h1.y);  DOT4W(6, h1.z);  DOT4W(7, h1.w);          \
    DOT4W(8, h2.x);  DOT4W(9, h2.y);  DOT4W(10, h2.z); DOT4W(11, h2.w);         \
    DOT4W(12, h3.x); DOT4W(13, h3.y); DOT4W(14, h3.z); DOT4W(15, h3.w);         \
    /* transpose-reduce: land gate l's full dot in lane l */                    \
    int rA0 = (l & 1) ? aA1 : aA0, gA0 = (l & 1) ? aA0 : aA1;                   \
    int rA1 = (l & 1) ? aA3 : aA2, gA1 = (l & 1) ? aA2 : aA3;                   \
    rA0 += dppi<0xB1>(gA0); rA1 += dppi<0xB1>(gA1);                             \
    int oAi = (l & 2) ? rA1 : rA0, gA2 = (l & 2) ? rA0 : rA1;                   \
    oAi += dppi<0x4E>(gA2);                                                     \
    int rB0 = (l & 1) ? aB1 : aB0, gB0 = (l & 1) ? aB0 : aB1;                   \
    int rB1 = (l & 1) ? aB3 : aB2, gB1 = (l & 1) ? aB2 : aB3;                   \
    rB0 += dppi<0xB1>(gB0); rB1 += dppi<0xB1>(gB1);                             \
    int oBi = (l & 2) ? rB1 : rB0, gB2 = (l & 2) ? rB0 : rB1;                   \
    oBi += dppi<0x4E>(gB2);                                                     \
    const float gfA = fmaf((float)oAi, dqA, (XA));                              \
    const float gfB = fmaf((float)oBi, dqB, (XB));                              \
    const float actA = fmaf(s_, rcp_(1.f + ex2(em * gfA)), d_);                 \
    const float actB = fmaf(s_, rcp_(1.f + ex2(em * gfB)), d_);                 \
    const float iA = dppf<0x00>(actA), fA = dppf<0x55>(actA);                   \
    const float gA = dppf<0xAA>(actA), oA = dppf<0xFF>(actA);                   \
    const float iB = dppf<0x00>(actB), fB = dppf<0x55>(actB);                   \
    const float gB = dppf<0xAA>(actB), oB = dppf<0xFF>(actB);                   \
    cA = fmaf(fA, cA, iA * gA);                                                 \
    cB = fmaf(fB, cB, iB * gB);                                                 \
    const float tcA = fmaf(2.f, rcp_(1.f + ex2(-2.885390082f * cA)), -1.f);     \
    const float tcB = fmaf(2.f, rcp_(1.f + ex2(-2.885390082f * cB)), -1.f);     \
    const float hnA = oA * tcA, hnB = oB * tcB;                                 \
    if (l == 0) {                                                               \
      const int qa = (int)rintf(hnA * 127.f) & 255;                             \
      const int qb = (int)rintf(hnB * 127.f) & 255;                             \
      ((unsigned short*)&hq[(CUR) ^ 1][0])[p] = (unsigned short)(qa | (qb << 8));\
    }                                                                           \
    if (l == 1) {                                                               \
      float2 h2v; h2v.x = hnA; h2v.y = hnB;                                     \
      *(float2*)(hout + (long)(T) * WHD) = h2v;                                 \
    }                                                                           \
    asm volatile("s_waitcnt lgkmcnt(0)\n\ts_barrier" ::: "memory");             \
  } while (0)

  float A0a = xbase[0],    A0b = xbase[512];
  float A1a = xbase[1024], A1b = xbase[1536];
  float A2a = xbase[2048], A2b = xbase[2560];
  float A3a = xbase[3072], A3b = xbase[3584];
  for (int t0 = 0; t0 < S_LEN; t0 += 8) {
    const float* pb = xbase + (long)(t0 + 4) * 1024;
    const float B0a = pb[0],    B0b = pb[512];
    const float B1a = pb[1024], B1b = pb[1536];
    const float B2a = pb[2048], B2b = pb[2560];
    const float B3a = pb[3072], B3b = pb[3584];
    STEP(t0 + 0, A0a, A0b, 0); STEP(t0 + 1, A1a, A1b, 1);
    STEP(t0 + 2, A2a, A2b, 0); STEP(t0 + 3, A3a, A3b, 1);
    if (t0 + 8 < S_LEN) {
      const float* pa = xbase + (long)(t0 + 8) * 1024;
      A0a = pa[0];    A0b = pa[512];
      A1a = pa[1024]; A1b = pa[1536];
      A2a = pa[2048]; A2b = pa[2560];
      A3a = pa[3072]; A3b = pa[3584];
    }
    STEP(t0 + 4, B0a, B0b, 0); STEP(t0 + 5, B1a, B1b, 1);
    STEP(t0 + 6, B2a, B2b, 0); STEP(t0 + 7, B3a, B3b, 1);
  }
#undef STEP
#undef DOT4W
}

// ---------------- Kernel 4: tag projection + log_softmax ------------------------
__global__ __launch_bounds__(64) void k_tag(
    const float* __restrict__ h_all, const float* __restrict__ tagW,
    const float* __restrict__ tagb, float* __restrict__ out) {
  __shared__ float hrow[WHD];
  const int s = blockIdx.x, t = threadIdx.x;
  for (int i = t; i < WHD; i += 64) hrow[i] = h_all[(long)s * WHD + i];
  __syncthreads();
  const float4* wr = (const float4*)(tagW + t * WHD);
  const float4* hr = (const float4*)hrow;
  float a = tagb[t];
#pragma unroll
  for (int i = 0; i < 64; ++i) {
    float4 w4 = wr[i], h4 = hr[i];
    a += w4.x * h4.x + w4.y * h4.y + w4.z * h4.z + w4.w * h4.w;
  }
  float m = a;
#pragma unroll
  for (int d = 1; d < 64; d <<= 1) m = fmaxf(m, __shfl_xor(m, d));
  const float e = __expf(a - m);
  float sum = e;
#pragma unroll
  for (int d = 1; d < 64; d <<= 1) sum += __shfl_xor(sum, d);
  out[(long)s * TAGV + t] = (a - m) - logf(sum);
}

extern "C" void kernel_launch(void* const* d_in, const int* in_sizes, int n_in,
                              void* d_out, int out_size, void* d_ws, size_t ws_size,
                              hipStream_t stream) {
  const int* sent       = (const int*)d_in[0];
  const int* chars      = (const int*)d_in[1];
  const int* char_lens  = (const int*)d_in[2];
  const float* char_emb = (const float*)d_in[3];
  const float* word_emb = (const float*)d_in[4];
  const float* cW_ih    = (const float*)d_in[5];
  const float* cW_hh    = (const float*)d_in[6];
  const float* cb_ih    = (const float*)d_in[7];
  const float* cb_hh    = (const float*)d_in[8];
  const float* wW_ih    = (const float*)d_in[9];
  const float* wW_hh    = (const float*)d_in[10];
  const float* wb_ih    = (const float*)d_in[11];
  const float* wb_hh    = (const float*)d_in[12];
  const float* tagW     = (const float*)d_in[13];
  const float* tagb     = (const float*)d_in[14];
  float* out = (float*)d_out;

  char* ws = (char*)d_ws;
  float* char_final = (float*)ws;                          // 4096*128*4  = 2 MB
  float* xp         = (float*)(ws + ((size_t)2 << 20));    // 4096*1024*4 = 16 MB
  float* h_all      = (float*)(ws + ((size_t)20 << 20));   // 4096*256*4  = 4 MB

  hipLaunchKernelGGL(k_char_lstm, dim3(512), dim3(256), 0, stream,
                     chars, char_lens, char_emb, cW_ih, cW_hh, cb_ih, cb_hh, char_final);
  hipLaunchKernelGGL(k_wxp, dim3(256), dim3(1024), 0, stream,
                     sent, word_emb, char_final, wW_ih, wb_ih, wb_hh, xp);
  hipLaunchKernelGGL(k_word_lstm, dim3(1), dim3(512), 0, stream, wW_hh, xp, h_all);
  hipLaunchKernelGGL(k_tag, dim3(4096), dim3(64), 0, stream, h_all, tagW, tagb, out);
}

// Round 4
// 4104.225 us; speedup vs baseline: 1.5536x; 1.0060x over previous
//
#include <hip/hip_runtime.h>

#define S_LEN 4096
#define LCH   16
#define CED   64
#define CHD   128
#define WED   256
#define WHD   256
#define TAGV  64

typedef _Float16 hf;
typedef _Float16 hf2 __attribute__((ext_vector_type(2)));

union PK2 { int i; hf2 h; };

__device__ __forceinline__ float dot2i(int a, int b, float acc) {
  PK2 ua, ub; ua.i = a; ub.i = b;
#if __has_builtin(__builtin_amdgcn_fdot2)
  return __builtin_amdgcn_fdot2(ua.h, ub.h, acc, false);
#else
  return acc + (float)ua.h.x * (float)ub.h.x + (float)ua.h.y * (float)ub.h.y;
#endif
}

__device__ __forceinline__ int dot4i8(int a, int b, int c) {
#if __has_builtin(__builtin_amdgcn_sdot4)
  return __builtin_amdgcn_sdot4(a, b, c, false);
#else
  int r = c;
  r += (int)(signed char)(a)       * (int)(signed char)(b);
  r += (int)(signed char)(a >> 8)  * (int)(signed char)(b >> 8);
  r += (int)(signed char)(a >> 16) * (int)(signed char)(b >> 16);
  r += (int)(signed char)(a >> 24) * (int)(signed char)(b >> 24);
  return r;
#endif
}

__device__ __forceinline__ float ex2(float x) {
#if __has_builtin(__builtin_amdgcn_exp2f)
  return __builtin_amdgcn_exp2f(x);
#else
  return __exp2f(x);
#endif
}
__device__ __forceinline__ float rcp_(float x) {
#if __has_builtin(__builtin_amdgcn_rcpf)
  return __builtin_amdgcn_rcpf(x);
#else
  return 1.f / x;
#endif
}

template <int C> __device__ __forceinline__ int dppi(int x) {
  return __builtin_amdgcn_mov_dpp(x, C, 0xf, 0xf, false);
}
template <int C> __device__ __forceinline__ float dppf(float x) {
  return __int_as_float(__builtin_amdgcn_mov_dpp(__float_as_int(x), C, 0xf, 0xf, false));
}
// quad_perm ctrl: xor1=0xB1, xor2=0x4E, bcast lane0..3 = 0x00,0x55,0xAA,0xFF

// fast sigmoid/tanh via v_exp_f32 + v_rcp_f32
__device__ __forceinline__ float fsig(float x) {        // sigmoid(x)
  return rcp_(1.f + ex2(-1.442695041f * x));
}
__device__ __forceinline__ float ftanh(float x) {       // tanh(x)
  return fmaf(2.f, rcp_(1.f + ex2(-2.885390082f * x)), -1.f);
}

// ---------------- Kernel 1: char LSTM (batch 4096, 16 steps, H=128) -------------
// 256 threads: u = tid>>1 gate-unit, kh = tid&1 K-half. 8 words/block.
// Weights int-packed (2xhf per VGPR); LDS reads via int4 (b128).
__global__ __launch_bounds__(256) void k_char_lstm(
    const int* __restrict__ chars, const int* __restrict__ char_lens,
    const float* __restrict__ char_emb,
    const float* __restrict__ cW_ih, const float* __restrict__ cW_hh,
    const float* __restrict__ cb_ih, const float* __restrict__ cb_hh,
    float* __restrict__ char_final) {
  __shared__ hf emb_s[128 * CED];      // 16 KB
  __shared__ hf h_s[2][8][CHD];        // 4 KB
  __shared__ int chars_s[8 * LCH];
  __shared__ int lens_s[8];

  const int tid = threadIdx.x;
  const int u = tid >> 1, kh = tid & 1;
  const int w0 = blockIdx.x * 8;

  for (int i = tid; i < 128 * CED; i += 256) emb_s[i] = (hf)char_emb[i];
  for (int i = tid; i < 8 * LCH; i += 256) chars_s[i] = chars[w0 * LCH + i];
  if (tid < 8) lens_s[tid] = char_lens[w0 + tid];
  {
    hf* hz = &h_s[0][0][0];
    for (int i = tid; i < 8 * CHD; i += 256) hz[i] = (hf)0.f;
  }

  int wih[4][16];   // 32 hf (K-half of 64) per gate
  int whh[4][32];   // 64 hf (K-half of 128) per gate
  float bq[4];
#pragma unroll
  for (int q = 0; q < 4; ++q) {
    const int r = q * CHD + u;
    const float* pi = cW_ih + r * CED + 32 * kh;
#pragma unroll
    for (int j = 0; j < 16; ++j) { PK2 v; v.h.x = (hf)pi[2*j]; v.h.y = (hf)pi[2*j+1]; wih[q][j] = v.i; }
    const float* ph = cW_hh + r * CHD + 64 * kh;
#pragma unroll
    for (int j = 0; j < 32; ++j) { PK2 v; v.h.x = (hf)ph[2*j]; v.h.y = (hf)ph[2*j+1]; whh[q][j] = v.i; }
    bq[q] = cb_ih[r] + cb_hh[r];
  }
  float c[8];
#pragma unroll
  for (int w = 0; w < 8; ++w) c[w] = 0.f;
  __syncthreads();

  for (int t = 0; t < LCH; ++t) {
    const int cur = t & 1, nxt = cur ^ 1;
#pragma unroll
    for (int w = 0; w < 8; ++w) {
      const int cidx = chars_s[w * LCH + t];
      const int4* xr4 = (const int4*)(emb_s + cidx * CED + 32 * kh);  // 64 B
      const int4* hr4 = (const int4*)(&h_s[cur][w][64 * kh]);         // 128 B
      int xi[16], hi[32];
#pragma unroll
      for (int j = 0; j < 4; ++j) *(int4*)(xi + 4 * j) = xr4[j];
#pragma unroll
      for (int j = 0; j < 8; ++j) *(int4*)(hi + 4 * j) = hr4[j];
      float a0 = 0.f, a1 = 0.f, a2 = 0.f, a3 = 0.f;
#pragma unroll
      for (int j = 0; j < 16; ++j) {
        a0 = dot2i(wih[0][j], xi[j], a0); a1 = dot2i(wih[1][j], xi[j], a1);
        a2 = dot2i(wih[2][j], xi[j], a2); a3 = dot2i(wih[3][j], xi[j], a3);
      }
#pragma unroll
      for (int j = 0; j < 32; ++j) {
        a0 = dot2i(whh[0][j], hi[j], a0); a1 = dot2i(whh[1][j], hi[j], a1);
        a2 = dot2i(whh[2][j], hi[j], a2); a3 = dot2i(whh[3][j], hi[j], a3);
      }
      // pair-reduce across kh (lanes tid^1, within quad)
      a0 += dppf<0xB1>(a0); a1 += dppf<0xB1>(a1);
      a2 += dppf<0xB1>(a2); a3 += dppf<0xB1>(a3);
      const float ig = fsig(a0 + bq[0]);
      const float fg = fsig(a1 + bq[1]);
      const float gg = ftanh(a2 + bq[2]);
      const float og = fsig(a3 + bq[3]);
      c[w] = fmaf(fg, c[w], ig * gg);
      const float hn = og * ftanh(c[w]);
      if (kh == 0) {
        h_s[nxt][w][u] = (hf)hn;
        if (t == lens_s[w] - 1) char_final[(w0 + w) * CHD + u] = hn;
      }
    }
    __syncthreads();
  }
}

// ---------------- Kernel 2: word-LSTM input part (parallel) ----------------------
// slot(tid): gate = 256*(tid&3) + (tid>>2)  [consumer thread t reads slot t]
__global__ __launch_bounds__(1024) void k_wxp(
    const int* __restrict__ sent, const float* __restrict__ word_emb,
    const float* __restrict__ char_final,
    const float* __restrict__ wW_ih, const float* __restrict__ wb_ih,
    const float* __restrict__ wb_hh, float* __restrict__ xp) {
  __shared__ float comb[16][WED + CHD];
  const int tid = threadIdx.x;
  const int s0 = blockIdx.x * 16;
  for (int i = tid; i < 16 * WED; i += 1024) {
    const int w = i / WED, k = i % WED;
    comb[w][k] = word_emb[(long)sent[s0 + w] * WED + k];
  }
  for (int i = tid; i < 16 * CHD; i += 1024) {
    const int w = i / CHD, k = i % CHD;
    comb[w][WED + k] = char_final[(s0 + w) * CHD + k];
  }
  __syncthreads();

  const int gate = 256 * (tid & 3) + (tid >> 2);
  const float bias = wb_ih[gate] + wb_hh[gate];
  float acc[16];
#pragma unroll
  for (int w = 0; w < 16; ++w) acc[w] = bias;
  const float* wrow = wW_ih + gate * (WED + CHD);
  for (int kc = 0; kc < WED + CHD; kc += 64) {
    const float4* wr4 = (const float4*)(wrow + kc);
    float4 wv[16];
#pragma unroll
    for (int i = 0; i < 16; ++i) wv[i] = wr4[i];
#pragma unroll
    for (int w = 0; w < 16; ++w) {
      const float4* cr = (const float4*)&comb[w][kc];
      float a = 0.f;
#pragma unroll
      for (int i = 0; i < 16; ++i) {
        float4 cv = cr[i];
        a += wv[i].x * cv.x + wv[i].y * cv.y + wv[i].z * cv.z + wv[i].w * cv.w;
      }
      acc[w] += a;
    }
  }
#pragma unroll
  for (int w = 0; w < 16; ++w) xp[(long)(s0 + w) * 1024 + tid] = acc[w];
}

// ---------------- Kernel 3: word LSTM recurrence (serial, 1 block) ---------------
// 1024 threads (16 waves, 4/SIMD). Quad p owns unit p; lane l = gate-type l over
// k-slice [64l,64l+64). 64 wq ints/thread -> fits arch-VGPR at 4 waves/SIMD.
// sdot4 dots, 9-inst transpose-reduce (gate l's full dot lands in lane l), one
// activation/lane, quad-bcast via DPP, c redundant in quad, h int8 in LDS
// flip-flop, lgkmcnt-only raw barrier, xp prefetched 4-8 steps ahead.
__global__ __launch_bounds__(1024, 4) void k_word_lstm(
    const float* __restrict__ wW_hh, const float* __restrict__ xp,
    float* __restrict__ h_all) {
  __shared__ int hq[2][WHD / 4];  // int8-packed h, 256 B per buffer
  const int t = threadIdx.x;
  const int p = t >> 2, l = t & 3;

  float m0, m1, m2, m3;
  int wq0[16], wq1[16], wq2[16], wq3[16];

#define ROWMAX(mdst, row) do {                                                  \
    const float4* wr_ = (const float4*)(wW_hh + (long)(row) * WHD + 64 * l);    \
    float m_ = 0.f;                                                             \
    _Pragma("unroll")                                                           \
    for (int j = 0; j < 16; ++j) {                                              \
      float4 v = wr_[j];                                                        \
      m_ = fmaxf(m_, fmaxf(fmaxf(fabsf(v.x), fabsf(v.y)),                       \
                           fmaxf(fabsf(v.z), fabsf(v.w))));                     \
    }                                                                           \
    m_ = fmaxf(m_, dppf<0xB1>(m_)); m_ = fmaxf(m_, dppf<0x4E>(m_));             \
    (mdst) = m_;                                                                \
  } while (0)

  ROWMAX(m0, 0 * WHD + p); ROWMAX(m1, 1 * WHD + p);
  ROWMAX(m2, 2 * WHD + p); ROWMAX(m3, 3 * WHD + p);
#undef ROWMAX

#define QROW(dst, row, mreg) do {                                               \
    const float4* wr_ = (const float4*)(wW_hh + (long)(row) * WHD + 64 * l);    \
    const float r_ = ((mreg) > 0.f) ? 127.f / (mreg) : 0.f;                     \
    _Pragma("unroll")                                                           \
    for (int j = 0; j < 16; ++j) {                                              \
      float4 v = wr_[j];                                                        \
      const int b0 = (int)rintf(v.x * r_) & 255;                                \
      const int b1 = (int)rintf(v.y * r_) & 255;                                \
      const int b2 = (int)rintf(v.z * r_) & 255;                                \
      const int b3 = (int)rintf(v.w * r_) & 255;                                \
      dst[j] = b0 | (b1 << 8) | (b2 << 16) | (b3 << 24);                        \
    }                                                                           \
  } while (0)

  QROW(wq0, 0 * WHD + p, m0); QROW(wq1, 1 * WHD + p, m1);
  QROW(wq2, 2 * WHD + p, m2); QROW(wq3, 3 * WHD + p, m3);
#undef QROW

  // own-gate (gate-type == l) dequant scale and act constants
  const float ma = (l & 1) ? m1 : m0;
  const float mb = (l & 1) ? m3 : m2;
  const float msel = (l & 2) ? mb : ma;
  const float dq = msel * (1.f / (127.f * 127.f));
  const float em = (l == 2) ? -2.885390082f : -1.442695041f;
  const float s_ = (l == 2) ? 2.f : 1.f;
  const float d_ = (l == 2) ? -1.f : 0.f;

  if (t < 128) ((int*)hq)[t] = 0;
  float c = 0.f;
  __syncthreads();

  const float* xbase = xp + t;  // slot t = gate 256l + p
  float* hout = h_all + p;

#define D4(j, W) do {                                                           \
    a0 = dot4i8(wq0[j], (W), a0); a1 = dot4i8(wq1[j], (W), a1);                 \
    a2 = dot4i8(wq2[j], (W), a2); a3 = dot4i8(wq3[j], (W), a3);                 \
  } while (0)

#define STEP(T, XV, CUR) do {                                                   \
    const int4* hp_ = (const int4*)(&hq[CUR][0]) + 4 * l;                       \
    int4 h0 = hp_[0], h1 = hp_[1], h2 = hp_[2], h3 = hp_[3];                    \
    int a0 = 0, a1 = 0, a2 = 0, a3 = 0;                                         \
    D4(0, h0.x);  D4(1, h0.y);  D4(2, h0.z);  D4(3, h0.w);                      \
    D4(4, h1.x);  D4(5, h1.y);  D4(6, h1.z);  D4(7, h1.w);                      \
    D4(8, h2.x);  D4(9, h2.y);  D4(10, h2.z); D4(11, h2.w);                     \
    D4(12, h3.x); D4(13, h3.y); D4(14, h3.z); D4(15, h3.w);                     \
    int r0 = (l & 1) ? a1 : a0, g0 = (l & 1) ? a0 : a1;                         \
    int r1 = (l & 1) ? a3 : a2, g1 = (l & 1) ? a2 : a3;                         \
    r0 += dppi<0xB1>(g0); r1 += dppi<0xB1>(g1);                                 \
    int oi = (l & 2) ? r1 : r0, g2 = (l & 2) ? r0 : r1;                         \
    oi += dppi<0x4E>(g2);                                                       \
    const float gf = fmaf((float)oi, dq, (XV));                                 \
    const float act = fmaf(s_, rcp_(1.f + ex2(em * gf)), d_);                   \
    const float i_ = dppf<0x00>(act), f_ = dppf<0x55>(act);                     \
    const float g_ = dppf<0xAA>(act), o_ = dppf<0xFF>(act);                     \
    c = fmaf(f_, c, i_ * g_);                                                   \
    const float tc = fmaf(2.f, rcp_(1.f + ex2(-2.885390082f * c)), -1.f);       \
    const float hn = o_ * tc;                                                   \
    if (l == 0) ((signed char*)&hq[(CUR) ^ 1][0])[p] =                          \
        (signed char)(int)rintf(hn * 127.f);                                    \
    if (l == 1) hout[(long)(T) * WHD] = hn;                                     \
    asm volatile("s_waitcnt lgkmcnt(0)\n\ts_barrier" ::: "memory");             \
  } while (0)

  float xA0 = xbase[0], xA1 = xbase[1024], xA2 = xbase[2048], xA3 = xbase[3072];
  for (int t0 = 0; t0 < S_LEN; t0 += 8) {
    const float* pb = xbase + (long)(t0 + 4) * 1024;
    const float xB0 = pb[0], xB1 = pb[1024], xB2 = pb[2048], xB3 = pb[3072];
    STEP(t0 + 0, xA0, 0); STEP(t0 + 1, xA1, 1);
    STEP(t0 + 2, xA2, 0); STEP(t0 + 3, xA3, 1);
    if (t0 + 8 < S_LEN) {
      const float* pa = xbase + (long)(t0 + 8) * 1024;
      xA0 = pa[0]; xA1 = pa[1024]; xA2 = pa[2048]; xA3 = pa[3072];
    }
    STEP(t0 + 4, xB0, 0); STEP(t0 + 5, xB1, 1);
    STEP(t0 + 6, xB2, 0); STEP(t0 + 7, xB3, 1);
  }
#undef STEP
#undef D4
}

// ---------------- Kernel 4: tag projection + log_softmax ------------------------
__global__ __launch_bounds__(64) void k_tag(
    const float* __restrict__ h_all, const float* __restrict__ tagW,
    const float* __restrict__ tagb, float* __restrict__ out) {
  __shared__ float hrow[WHD];
  const int s = blockIdx.x, t = threadIdx.x;
  for (int i = t; i < WHD; i += 64) hrow[i] = h_all[(long)s * WHD + i];
  __syncthreads();
  const float4* wr = (const float4*)(tagW + t * WHD);
  const float4* hr = (const float4*)hrow;
  float a = tagb[t];
#pragma unroll
  for (int i = 0; i < 64; ++i) {
    float4 w4 = wr[i], h4 = hr[i];
    a += w4.x * h4.x + w4.y * h4.y + w4.z * h4.z + w4.w * h4.w;
  }
  float m = a;
#pragma unroll
  for (int d = 1; d < 64; d <<= 1) m = fmaxf(m, __shfl_xor(m, d));
  const float e = __expf(a - m);
  float sum = e;
#pragma unroll
  for (int d = 1; d < 64; d <<= 1) sum += __shfl_xor(sum, d);
  out[(long)s * TAGV + t] = (a - m) - logf(sum);
}

extern "C" void kernel_launch(void* const* d_in, const int* in_sizes, int n_in,
                              void* d_out, int out_size, void* d_ws, size_t ws_size,
                              hipStream_t stream) {
  const int* sent       = (const int*)d_in[0];
  const int* chars      = (const int*)d_in[1];
  const int* char_lens  = (const int*)d_in[2];
  const float* char_emb = (const float*)d_in[3];
  const float* word_emb = (const float*)d_in[4];
  const float* cW_ih    = (const float*)d_in[5];
  const float* cW_hh    = (const float*)d_in[6];
  const float* cb_ih    = (const float*)d_in[7];
  const float* cb_hh    = (const float*)d_in[8];
  const float* wW_ih    = (const float*)d_in[9];
  const float* wW_hh    = (const float*)d_in[10];
  const float* wb_ih    = (const float*)d_in[11];
  const float* wb_hh    = (const float*)d_in[12];
  const float* tagW     = (const float*)d_in[13];
  const float* tagb     = (const float*)d_in[14];
  float* out = (float*)d_out;

  char* ws = (char*)d_ws;
  float* char_final = (float*)ws;                          // 4096*128*4  = 2 MB
  float* xp         = (float*)(ws + ((size_t)2 << 20));    // 4096*1024*4 = 16 MB
  float* h_all      = (float*)(ws + ((size_t)20 << 20));   // 4096*256*4  = 4 MB

  hipLaunchKernelGGL(k_char_lstm, dim3(512), dim3(256), 0, stream,
                     chars, char_lens, char_emb, cW_ih, cW_hh, cb_ih, cb_hh, char_final);
  hipLaunchKernelGGL(k_wxp, dim3(256), dim3(1024), 0, stream,
                     sent, word_emb, char_final, wW_ih, wb_ih, wb_hh, xp);
  hipLaunchKernelGGL(k_word_lstm, dim3(1), dim3(1024), 0, stream, wW_hh, xp, h_all);
  hipLaunchKernelGGL(k_tag, dim3(4096), dim3(64), 0, stream, h_all, tagW, tagb, out);
}